// Round 11
// baseline (1186.649 us; speedup 1.0000x reference)
//
#include <hip/hip_runtime.h>

// QuantumDenseNet R11: R10 structure (512 thr, photon-block mask-split,
// strides {6,1,36,221,1334}, 32 waves/CU) + (a) swapped-operand complex MAC
// via inline-asm v_pk_fma_f16 op_sel:[0,1,0] op_sel_hi:[1,0,1] (= a*swap(b)+c
// in ONE inst -- removes any explicit swap VALU), (b) first MAC term peeled
// to v_pk_mul_f16 (no acc zero-init), (c) gates+dcol merged into one prep
// kernel (one launch fewer, overlapped).

typedef float    vf2 __attribute__((ext_vector_type(2)));
typedef _Float16 h2  __attribute__((ext_vector_type(2)));

__device__ __forceinline__ h2 pkfma(const h2 a, const h2 b, const h2 c) {
    return __builtin_elementwise_fma(a, b, c);
}
// d = a * swap(b) + c, single VOP3P via op_sel
__device__ __forceinline__ h2 pkfma_sw(const h2 a, const h2 b, const h2 c) {
    unsigned int ai = __builtin_bit_cast(unsigned int, a);
    unsigned int bi = __builtin_bit_cast(unsigned int, b);
    unsigned int ci = __builtin_bit_cast(unsigned int, c);
    unsigned int di;
    asm("v_pk_fma_f16 %0, %1, %2, %3 op_sel:[0,1,0] op_sel_hi:[1,0,1]"
        : "=v"(di) : "v"(ai), "v"(bi), "v"(ci));
    return __builtin_bit_cast(h2, di);
}
__device__ __forceinline__ vf2 h2f(const h2 h) { return (vf2){(float)h.x, (float)h.y}; }

__device__ __forceinline__ void cmadd(float &ax, float &ay, const float2 u, const float2 v) {
    ax = fmaf(u.x, v.x, ax);
    ax = fmaf(-u.y, v.y, ax);
    ay = fmaf(u.x, v.y, ay);
    ay = fmaf(u.y, v.x, ay);
}

// block-diagonal structure of the 36x36 BS gate (total photon number n=0..10)
constexpr int BS_SN[11]  = {1,2,3,4,5,6,5,4,3,2,1};
constexpr int BS_OFF[11] = {0,1,5,14,30,55,91,116,132,141,145};
// thread-half block masks: A = {0,1,4,5,9,10} (71 cMAC), B = {2,3,6,7,8} (75)
constexpr unsigned MASK_A = (1u<<0)|(1u<<1)|(1u<<4)|(1u<<5)|(1u<<9)|(1u<<10);
constexpr unsigned MASK_B = (1u<<2)|(1u<<3)|(1u<<6)|(1u<<7)|(1u<<8);
// mode strides (h2 units): {6, 1, 36, 221, 1334} -- mode3/4 padded for banks

// runtime-indexed copy for prep_kernel packing
__device__ const int d_BS_OFF[12] = {0,1,5,14,30,55,91,116,132,141,145,146};
__device__ const int d_BS_SN[11]  = {1,2,3,4,5,6,5,4,3,2,1};

// ---------------------------------------------------------------------------
// Merged precompute: blocks 0..79 -> BS gates (292 h2, pairs {ur,ur},{-ui,ui});
// block 80 -> 40 single-mode combined gates (72 h2); blocks 81.. -> dcol
// (initial-displacement expm column 0 per (batch,mode)).
// ---------------------------------------------------------------------------
__global__ void prep_kernel(const float* __restrict__ x,
                            const float* __restrict__ lin,
                            const float* __restrict__ act,
                            const float* __restrict__ lact,
                            h2* __restrict__ bsh,
                            h2* __restrict__ sgh,
                            float* __restrict__ dcol, const int total)
{
    __shared__ float2 B0[1296];
    __shared__ float2 B1[1296];
    const int tid = threadIdx.x;

    if (blockIdx.x < 80) {
        const int g = blockIdx.x;
        const int l = g / 20;
        const int w = g % 20;
        const int q = w / 10;
        const int n = w % 10;
        const float theta = lin[l*63 + (q ? 29 : 0) + n];
        const float phi   = lin[l*63 + (q ? 39 : 10) + n];
        const float ts = theta * 0.015625f;
        const float cp = cosf(phi), sp = sinf(phi);
        const float2 u  = make_float2( ts*cp, ts*sp);
        const float2 w2 = make_float2(-ts*cp, ts*sp);

        float2 *R = B0, *T = B1;
        for (int e = tid; e < 1296; e += 256)
            R[e] = make_float2((e % 37 == 0) ? 1.f : 0.f, 0.f);
        __syncthreads();

        for (int k = 16; k >= 1; --k) {
            const float invk = 1.f / (float)k;
            for (int e = tid; e < 1296; e += 256) {
                const int row = e / 36, c = e - row*36;
                const int i = row / 6, j = row - (row/6)*6;
                float ax = 0.f, ay = 0.f;
                if (i < 5 && j > 0) {
                    const float coef = sqrtf((float)((i+1)*j));
                    const float2 xx = R[(row+5)*36 + c];
                    const float px = u.x*xx.x - u.y*xx.y;
                    const float py = u.x*xx.y + u.y*xx.x;
                    ax = fmaf(coef, px, ax); ay = fmaf(coef, py, ay);
                }
                if (i > 0 && j < 5) {
                    const float coef = sqrtf((float)(i*(j+1)));
                    const float2 xx = R[(row-5)*36 + c];
                    const float px = w2.x*xx.x - w2.y*xx.y;
                    const float py = w2.x*xx.y + w2.y*xx.x;
                    ax = fmaf(coef, px, ax); ay = fmaf(coef, py, ay);
                }
                T[e] = make_float2(((row == c) ? 1.f : 0.f) + ax*invk, ay*invk);
            }
            __syncthreads();
            float2* tmp = R; R = T; T = tmp;
        }
        for (int s2 = 0; s2 < 6; ++s2) {
            for (int e = tid; e < 1296; e += 256) {
                const int row = e / 36, c = e - row*36;
                float ax = 0.f, ay = 0.f;
                #pragma unroll 6
                for (int k = 0; k < 36; ++k)
                    cmadd(ax, ay, R[row*36 + k], R[k*36 + c]);
                T[e] = make_float2(ax, ay);
            }
            __syncthreads();
            float2* tmp = R; R = T; T = tmp;
        }
        for (int idx = tid; idx < 146; idx += 256) {
            int nn = 0;
            while (idx >= d_BS_OFF[nn+1]) ++nn;
            const int sn  = d_BS_SN[nn];
            const int rel = idx - d_BS_OFF[nn];
            const int p = rel / sn, qq = rel % sn;
            const int imin = (nn > 5) ? (nn - 5) : 0;
            const int row = 5*(imin + p)  + nn;
            const int col = 5*(imin + qq) + nn;
            const float2 z = R[row*36 + col];
            bsh[g*292 + 2*idx    ] = (h2){(_Float16)z.x,  (_Float16)z.x};
            bsh[g*292 + 2*idx + 1] = (h2){(_Float16)(-z.y), (_Float16)z.y};
        }
    } else if (blockIdx.x == 80) {
        const int t = tid;
        if (t >= 40) return;
        const int l  = t / 10;
        const int gi = t % 10;
        float2 G[36];
        if (gi < 5) {
            // Sq[m] = squeeze(r) @ diag(e^{i rphi1 * n})  (parity-banded)
            const int m = gi;
            const float r    = lin[l*63 + 24 + m];
            const float rphi = (m < 4) ? lin[l*63 + 20 + m] : 0.f;
            float R[36], T[36];
            #pragma unroll
            for (int e = 0; e < 36; ++e) R[e] = (e % 7 == 0) ? 1.f : 0.f;
            float hp[4];
            #pragma unroll
            for (int i = 0; i < 4; ++i)
                hp[i] = 0.5f * r * sqrtf((float)((i+1)*(i+2))) * 0.015625f;
            for (int k = 16; k >= 1; --k) {
                const float invk = 1.f / (float)k;
                #pragma unroll
                for (int i = 0; i < 6; ++i) {
                    #pragma unroll
                    for (int c = 0; c < 6; ++c) {
                        float a = 0.f;
                        if (i < 4)  a = fmaf( hp[i],   R[(i+2)*6 + c], a);
                        if (i >= 2) a = fmaf(-hp[i-2], R[(i-2)*6 + c], a);
                        T[i*6+c] = ((i == c) ? 1.f : 0.f) + a*invk;
                    }
                }
                #pragma unroll
                for (int e = 0; e < 36; ++e) R[e] = T[e];
            }
            for (int s2 = 0; s2 < 6; ++s2) {
                #pragma unroll
                for (int i = 0; i < 6; ++i) {
                    #pragma unroll
                    for (int c = 0; c < 6; ++c) {
                        float a = 0.f;
                        #pragma unroll
                        for (int k = 0; k < 6; ++k) a = fmaf(R[i*6+k], R[k*6+c], a);
                        T[i*6+c] = a;
                    }
                }
                #pragma unroll
                for (int e = 0; e < 36; ++e) R[e] = T[e];
            }
            #pragma unroll
            for (int c = 0; c < 6; ++c) {
                const float cc = cosf(rphi * (float)c), ss = sinf(rphi * (float)c);
                #pragma unroll
                for (int o = 0; o < 6; ++o)
                    G[o*6 + c] = make_float2(R[o*6+c]*cc, R[o*6+c]*ss);
            }
        } else {
            // Dp[m] = diag(e^{i kap n^2}) @ disp(dr,dp) @ diag(e^{i rphi2 n})
            const int m = gi - 5;
            const float dr   = lin[l*63 + 53 + m];
            const float dp   = lin[l*63 + 58 + m];
            const float rphi = (m < 4) ? lin[l*63 + 49 + m] : 0.f;
            const float kap  = (l < 3) ? act[l*5 + m] : ((m < 2) ? lact[m] : 0.f);
            const float2 al = make_float2(dr * cosf(dp), dr * sinf(dp));
            float2 R[36], T[36];
            #pragma unroll
            for (int e = 0; e < 36; ++e)
                R[e] = make_float2((e % 7 == 0) ? 1.f : 0.f, 0.f);
            float2 cm[6], cpb[6];
            #pragma unroll
            for (int i = 0; i < 6; ++i) {
                const float sm  = sqrtf((float)i)     * 0.015625f;
                const float sp2 = sqrtf((float)(i+1)) * 0.015625f;
                cm[i]  = make_float2( al.x*sm,  al.y*sm);
                cpb[i] = make_float2(-al.x*sp2, al.y*sp2);
            }
            for (int k = 16; k >= 1; --k) {
                const float invk = 1.f / (float)k;
                #pragma unroll
                for (int i = 0; i < 6; ++i) {
                    #pragma unroll
                    for (int c = 0; c < 6; ++c) {
                        float ax = 0.f, ay = 0.f;
                        if (i >= 1) cmadd(ax, ay, cm[i],  R[(i-1)*6 + c]);
                        if (i < 5)  cmadd(ax, ay, cpb[i], R[(i+1)*6 + c]);
                        T[i*6+c] = make_float2(((i == c) ? 1.f : 0.f) + ax*invk, ay*invk);
                    }
                }
                #pragma unroll
                for (int e = 0; e < 36; ++e) R[e] = T[e];
            }
            for (int s2 = 0; s2 < 6; ++s2) {
                #pragma unroll
                for (int i = 0; i < 6; ++i) {
                    #pragma unroll
                    for (int c = 0; c < 6; ++c) {
                        float ax = 0.f, ay = 0.f;
                        #pragma unroll
                        for (int k = 0; k < 6; ++k) cmadd(ax, ay, R[i*6+k], R[k*6+c]);
                        T[i*6+c] = make_float2(ax, ay);
                    }
                }
                #pragma unroll
                for (int e = 0; e < 36; ++e) R[e] = T[e];
            }
            #pragma unroll
            for (int o = 0; o < 6; ++o) {
                const float ko = kap * (float)(o*o);
                const float2 kp = make_float2(cosf(ko), sinf(ko));
                #pragma unroll
                for (int c = 0; c < 6; ++c) {
                    const float rc = rphi * (float)c;
                    const float2 rp = make_float2(cosf(rc), sinf(rc));
                    const float2 z = R[o*6 + c];
                    const float2 t1 = make_float2(kp.x*z.x - kp.y*z.y, kp.x*z.y + kp.y*z.x);
                    G[o*6 + c] = make_float2(t1.x*rp.x - t1.y*rp.y, t1.x*rp.y + t1.y*rp.x);
                }
            }
        }
        h2* outp = sgh + (l*10 + gi)*72;
        #pragma unroll
        for (int e = 0; e < 36; ++e) {
            outp[2*e    ] = (h2){(_Float16)G[e].x,  (_Float16)G[e].x};
            outp[2*e + 1] = (h2){(_Float16)(-G[e].y), (_Float16)G[e].y};
        }
    } else {
        // dcol: initial displacement (phi=0 -> real expm), column 0
        const int i = (blockIdx.x - 81) * 256 + tid;
        if (i >= total) return;
        const float xv = x[i];
        float a[5];
        #pragma unroll
        for (int j = 0; j < 5; ++j) a[j] = xv * sqrtf((float)(j+1)) * 0.015625f;
        float R[36], T[36];
        #pragma unroll
        for (int e = 0; e < 36; ++e) R[e] = (e % 7 == 0) ? 1.f : 0.f;
        for (int k = 16; k >= 1; --k) {
            const float invk = 1.f / (float)k;
            #pragma unroll
            for (int r = 0; r < 6; ++r) {
                #pragma unroll
                for (int c = 0; c < 6; ++c) {
                    float acc = 0.f;
                    if (r >= 1) acc = fmaf( a[r-1], R[(r-1)*6 + c], acc);
                    if (r < 5)  acc = fmaf(-a[r],   R[(r+1)*6 + c], acc);
                    T[r*6+c] = ((r == c) ? 1.f : 0.f) + acc*invk;
                }
            }
            #pragma unroll
            for (int e = 0; e < 36; ++e) R[e] = T[e];
        }
        for (int s2 = 0; s2 < 6; ++s2) {
            #pragma unroll
            for (int r = 0; r < 6; ++r) {
                #pragma unroll
                for (int c = 0; c < 6; ++c) {
                    float acc = 0.f;
                    #pragma unroll
                    for (int k = 0; k < 6; ++k) acc = fmaf(R[r*6+k], R[k*6+c], acc);
                    T[r*6+c] = acc;
                }
            }
            #pragma unroll
            for (int e = 0; e < 36; ++e) R[e] = T[e];
        }
        #pragma unroll
        for (int j = 0; j < 6; ++j) dcol[i*6 + j] = R[j*6 + 0];
    }
}

// ---------------------------------------------------------------------------
// Main kernel building blocks
// ---------------------------------------------------------------------------

// BS pass, block-partitioned: thread executes photon blocks selected by the
// runtime (wave-uniform) mask. Disjoint reads AND writes across halves.
// Complex MAC: pk_mul (first term) + pk_fma / pk_fma-op_sel-swap.
template<int SA, int SB, int n>
struct BDm {
    static __device__ __forceinline__ void run(const h2* __restrict__ U,
                                               h2* __restrict__ psi,
                                               const int base, const bool act,
                                               const unsigned mask) {
        if (mask & (1u << n)) {
            constexpr int sn = BS_SN[n], uoff = BS_OFF[n];
            constexpr int imin = (n > 5) ? (n - 5) : 0;
            h2 vb[sn];
            #pragma unroll
            for (int q = 0; q < sn; ++q) {
                const int c = 5*(imin + q) + n;
                vb[q] = psi[base + (c/6)*SA + (c%6)*SB];
            }
            h2 ob[sn];
            #pragma unroll
            for (int p = 0; p < sn; ++p) {
                h2 acc = U[2*(uoff + p*sn)] * vb[0];
                acc = pkfma_sw(U[2*(uoff + p*sn) + 1], vb[0], acc);
                #pragma unroll
                for (int q = 1; q < sn; ++q) {
                    acc = pkfma   (U[2*(uoff + p*sn + q)    ], vb[q], acc);
                    acc = pkfma_sw(U[2*(uoff + p*sn + q) + 1], vb[q], acc);
                }
                ob[p] = acc;
            }
            if (act) {
                #pragma unroll
                for (int p = 0; p < sn; ++p) {
                    const int c = 5*(imin + p) + n;
                    psi[base + (c/6)*SA + (c%6)*SB] = ob[p];
                }
            }
        }
        BDm<SA, SB, n+1>::run(U, psi, base, act, mask);
    }
};
template<int SA, int SB>
struct BDm<SA, SB, 11> {
    static __device__ __forceinline__ void run(const h2*, h2*, int, bool, unsigned) {}
};

template<int SA, int SB>
__device__ __forceinline__ void pass_bs(const h2* __restrict__ U,
                                        h2* __restrict__ psi,
                                        const int base, const bool act,
                                        const unsigned mask)
{
    BDm<SA, SB, 0>::run(U, psi, base, act, mask);
    __syncthreads();
}

// single-mode gate pass: 432 active threads x 3 mode-fibers of 6 (stride SM).
// S0..S3: spectator strides (ascending digit order). SP: parity-sparse.
template<int SM, int S0, int S1, int S2, int S3, bool SP>
__device__ __forceinline__ void pass_sg(const h2* __restrict__ G,
                                        h2* __restrict__ psi,
                                        const int aidx, const bool act)
{
    #pragma unroll
    for (int j = 0; j < 3; ++j) {
        const int g = aidx + j*432;
        const int d0 = g % 6; int t = g / 6;
        const int d1 = t % 6; t /= 6;
        const int d2 = t % 6; const int d3 = t / 6;
        const int base = d0*S0 + d1*S1 + d2*S2 + d3*S3;
        h2 vb[6];
        #pragma unroll
        for (int k = 0; k < 6; ++k) vb[k] = psi[base + k*SM];
        h2 o6[6];
        #pragma unroll
        for (int o = 0; o < 6; ++o) {
            const int k0 = SP ? (o & 1) : 0;
            const int st = SP ? 2 : 1;
            h2 acc = G[2*(o*6 + k0)] * vb[k0];
            acc = pkfma_sw(G[2*(o*6 + k0) + 1], vb[k0], acc);
            #pragma unroll
            for (int k = k0 + st; k < 6; k += st) {
                acc = pkfma   (G[2*(o*6 + k)    ], vb[k], acc);
                acc = pkfma_sw(G[2*(o*6 + k) + 1], vb[k], acc);
            }
            o6[o] = acc;
        }
        if (act) {
            #pragma unroll
            for (int o = 0; o < 6; ++o) psi[base + o*SM] = o6[o];
        }
    }
    __syncthreads();
}

__global__ __launch_bounds__(512, 8)
void qnet_kernel(const h2* __restrict__ bs,
                 const h2* __restrict__ sg,
                 const float* __restrict__ dcol,
                 float* __restrict__ out)
{
    // addr = 6*i0 + i1 + 36*i2 + 221*i3 + 1334*i4 (max 7990); scratch after
    __shared__ __align__(16) h2 psi[8088];   // 32352 B -> 4 blocks x 8 waves/CU
    const int tid = threadIdx.x;
    const int b   = blockIdx.x;

    float* stf = (float*)(psi + 7992);   // 30 floats (h2 units 7992..8051)
    float* red = (float*)(psi + 8052);   // 16 floats (h2 units 8052..8083)

    if (tid < 30) stf[tid] = dcol[b*30 + tid];
    __syncthreads();
    for (int e = tid; e < 7776; e += 512) {
        int t = e;
        const int i4 = t % 6; t /= 6;
        const int i3 = t % 6; t /= 6;
        const int i2 = t % 6; t /= 6;
        const int i1 = t % 6; t /= 6;
        const int i0 = t;
        const int addr = 6*i0 + i1 + 36*i2 + 221*i3 + 1334*i4;
        const float val = stf[i0]*stf[6+i1]*stf[12+i2]*stf[18+i3]*stf[24+i4];
        psi[addr] = (h2){(_Float16)val, (_Float16)0.f};
    }
    __syncthreads();

    // thread mapping: two halves of 256; sub<216 active; fiber f = sub
    const int sub   = tid & 255;
    const int halfT = tid >> 8;                 // wave-uniform
    const bool act  = sub < 216;
    const int f = act ? sub : 215;
    const int fa = f / 36, rem = f - fa*36;
    const int fb = rem / 6, fc = rem - fb*6;
    const int baseK0 = fa*36 + fb*221 + fc*1334;   // pair (0,1): spect 2,3,4
    const int baseK1 = fa*6  + fb*221 + fc*1334;   // pair (1,2): spect 0,3,4
    const int baseK2 = rem   + fa*1334;            // pair (2,3): spect 0,1 (contig), 4
    const int baseK3 = f;                          // pair (3,4): spect 0,1,2 (contig)
    const unsigned mask = halfT ? MASK_B : MASK_A;
    const int aidx = halfT*216 + f;                // 0..431 for single passes

    for (int l = 0; l < 4; ++l) {
        const h2* bsl = bs + l * 20 * 292;
        const h2* sgl = sg + l * 10 * 72;
        for (int hf = 0; hf < 2; ++hf) {
            const h2* bh = bsl + hf * 10 * 292;
            const h2* sh = sgl + hf * 5 * 72;
            // rail order k = {0,2,1,3,0,2,1,3,0,2}
            pass_bs<6,1>     (bh + 0*292, psi, baseK0, act, mask);
            pass_bs<36,221>  (bh + 1*292, psi, baseK2, act, mask);
            pass_bs<1,36>    (bh + 2*292, psi, baseK1, act, mask);
            pass_bs<221,1334>(bh + 3*292, psi, baseK3, act, mask);
            pass_bs<6,1>     (bh + 4*292, psi, baseK0, act, mask);
            pass_bs<36,221>  (bh + 5*292, psi, baseK2, act, mask);
            pass_bs<1,36>    (bh + 6*292, psi, baseK1, act, mask);
            pass_bs<221,1334>(bh + 7*292, psi, baseK3, act, mask);
            pass_bs<6,1>     (bh + 8*292, psi, baseK0, act, mask);
            pass_bs<36,221>  (bh + 9*292, psi, baseK2, act, mask);
            if (hf == 0) {   // squeeze gates: parity-sparse
                pass_sg<6,    1,36,221,1334, true>(sh + 0*72, psi, aidx, act);
                pass_sg<1,    6,36,221,1334, true>(sh + 1*72, psi, aidx, act);
                pass_sg<36,   1,6,221,1334,  true>(sh + 2*72, psi, aidx, act);
                pass_sg<221,  1,6,36,1334,   true>(sh + 3*72, psi, aidx, act);
                pass_sg<1334, 1,6,36,221,    true>(sh + 4*72, psi, aidx, act);
            } else {         // displacement gates: dense
                pass_sg<6,    1,36,221,1334, false>(sh + 0*72, psi, aidx, act);
                pass_sg<1,    6,36,221,1334, false>(sh + 1*72, psi, aidx, act);
                pass_sg<36,   1,6,221,1334,  false>(sh + 2*72, psi, aidx, act);
                pass_sg<221,  1,6,36,1334,   false>(sh + 3*72, psi, aidx, act);
                pass_sg<1334, 1,6,36,221,    false>(sh + 4*72, psi, aidx, act);
            }
        }
    }

    // <psi| X psi> on modes 0 (stride 6) and 1 (stride 1)
    float s0 = 0.f, s1 = 0.f;
    for (int fr = tid; fr < 1296; fr += 512) {
        const int q0 = fr % 6;
        const int q1 = (fr / 6) % 6;
        const int q2 = (fr / 36) % 6;
        const int q3 = fr / 216;
        const int base0 = q0*1 + q1*36 + q2*221 + q3*1334;   // spectators of mode 0
        #pragma unroll
        for (int j = 0; j < 5; ++j) {
            const vf2 p0 = h2f(psi[base0 + 6*j]);
            const vf2 p1 = h2f(psi[base0 + 6*(j+1)]);
            s0 = fmaf(sqrtf((float)(j+1)), fmaf(p0.y, p1.y, p0.x*p1.x), s0);
        }
        const int base1 = q0*6 + q1*36 + q2*221 + q3*1334;   // spectators of mode 1
        #pragma unroll
        for (int j = 0; j < 5; ++j) {
            const vf2 p0 = h2f(psi[base1 + j]);
            const vf2 p1 = h2f(psi[base1 + j + 1]);
            s1 = fmaf(sqrtf((float)(j+1)), fmaf(p0.y, p1.y, p0.x*p1.x), s1);
        }
    }
    #pragma unroll
    for (int off = 32; off > 0; off >>= 1) {
        s0 += __shfl_down(s0, off, 64);
        s1 += __shfl_down(s1, off, 64);
    }
    if ((tid & 63) == 0) { red[(tid>>6)*2] = s0; red[(tid>>6)*2 + 1] = s1; }
    __syncthreads();
    if (tid == 0) {
        float r0 = 0.f, r1 = 0.f;
        #pragma unroll
        for (int w = 0; w < 8; ++w) { r0 += red[2*w]; r1 += red[2*w + 1]; }
        out[b*2 + 0] = 2.f * r0;
        out[b*2 + 1] = 2.f * r1;
    }
}

// ---------------------------------------------------------------------------
extern "C" void kernel_launch(void* const* d_in, const int* in_sizes, int n_in,
                              void* d_out, int out_size, void* d_ws, size_t ws_size,
                              hipStream_t stream)
{
    const float* x    = (const float*)d_in[0];   // (B, 5)
    const float* lin  = (const float*)d_in[1];   // (4, 63)
    const float* act  = (const float*)d_in[2];   // (3, 5)
    const float* lact = (const float*)d_in[3];   // (5,)
    float* out = (float*)d_out;                  // (B, 2) float32

    const int B = in_sizes[0] / 5;

    // ws layout: 80 BS gates (292 h2) | 40 single gates (72 h2) | dcol f32
    h2*    bsh = (h2*)d_ws;
    h2*    sgh = bsh + 80*292;
    float* dc  = (float*)(sgh + 40*72);

    const int total = B * 5;
    const int nb = 81 + (total + 255) / 256;
    prep_kernel<<<dim3(nb), dim3(256), 0, stream>>>(x, lin, act, lact, bsh, sgh, dc, total);
    qnet_kernel<<<dim3(B), dim3(512), 0, stream>>>(bsh, sgh, dc, out);
}

// Round 12
// 909.134 us; speedup vs baseline: 1.3053x; 1.3053x over previous
//
#include <hip/hip_runtime.h>

// QuantumDenseNet R12: R10 structure restored (512 thr, photon-block
// mask-split, strides {6,1,36,221,1334}, 32 waves/CU, plain-C pkfma+swp --
// R11's inline-asm op_sel regressed 30% by defeating SGPR operand folding).
// Deltas: (a) exact 73/73 cMAC masks A={0,1,3,5,7} B={2,4,6,8,9,10} (was
// 71/75 -- B was critical path), (b) first MAC term peeled to mul in C.

typedef float    vf2 __attribute__((ext_vector_type(2)));
typedef _Float16 h2  __attribute__((ext_vector_type(2)));

__device__ __forceinline__ h2 pkfma(const h2 a, const h2 b, const h2 c) {
    return __builtin_elementwise_fma(a, b, c);
}
__device__ __forceinline__ h2 swp(const h2 v) {
    return __builtin_shufflevector(v, v, 1, 0);
}
__device__ __forceinline__ vf2 h2f(const h2 h) { return (vf2){(float)h.x, (float)h.y}; }

__device__ __forceinline__ void cmadd(float &ax, float &ay, const float2 u, const float2 v) {
    ax = fmaf(u.x, v.x, ax);
    ax = fmaf(-u.y, v.y, ax);
    ay = fmaf(u.x, v.y, ay);
    ay = fmaf(u.y, v.x, ay);
}

// block-diagonal structure of the 36x36 BS gate (total photon number n=0..10)
constexpr int BS_SN[11]  = {1,2,3,4,5,6,5,4,3,2,1};
constexpr int BS_OFF[11] = {0,1,5,14,30,55,91,116,132,141,145};
// thread-half block masks, exactly balanced at 73/73 cMAC:
//   A = {0,1,3,5,7}: 1+4+16+36+16 = 73 cMAC, 17 elems
//   B = {2,4,6,8,9,10}: 9+25+25+9+4+1 = 73 cMAC, 19 elems
constexpr unsigned MASK_A = (1u<<0)|(1u<<1)|(1u<<3)|(1u<<5)|(1u<<7);
constexpr unsigned MASK_B = (1u<<2)|(1u<<4)|(1u<<6)|(1u<<8)|(1u<<9)|(1u<<10);
// mode strides (h2 units): {6, 1, 36, 221, 1334} -- mode3/4 padded for banks

// runtime-indexed copy for gates_kernel packing
__device__ const int d_BS_OFF[12] = {0,1,5,14,30,55,91,116,132,141,145,146};
__device__ const int d_BS_SN[11]  = {1,2,3,4,5,6,5,4,3,2,1};

// ---------------------------------------------------------------------------
// Gate precompute (same as R10): blocks 0..79 -> BS gates packed block-diag as
// h2 pk-fma pairs {ur,ur},{-ui,ui} (292 h2/gate); block 80 -> 40 single-mode
// combined gates (72 h2/gate).
// ---------------------------------------------------------------------------
__global__ void gates_kernel(const float* __restrict__ lin,
                             const float* __restrict__ act,
                             const float* __restrict__ lact,
                             h2* __restrict__ bsh,
                             h2* __restrict__ sgh)
{
    __shared__ float2 B0[1296];
    __shared__ float2 B1[1296];
    const int tid = threadIdx.x;

    if (blockIdx.x < 80) {
        const int g = blockIdx.x;
        const int l = g / 20;
        const int w = g % 20;
        const int q = w / 10;
        const int n = w % 10;
        const float theta = lin[l*63 + (q ? 29 : 0) + n];
        const float phi   = lin[l*63 + (q ? 39 : 10) + n];
        const float ts = theta * 0.015625f;
        const float cp = cosf(phi), sp = sinf(phi);
        const float2 u  = make_float2( ts*cp, ts*sp);
        const float2 w2 = make_float2(-ts*cp, ts*sp);

        float2 *R = B0, *T = B1;
        for (int e = tid; e < 1296; e += 256)
            R[e] = make_float2((e % 37 == 0) ? 1.f : 0.f, 0.f);
        __syncthreads();

        for (int k = 16; k >= 1; --k) {
            const float invk = 1.f / (float)k;
            for (int e = tid; e < 1296; e += 256) {
                const int row = e / 36, c = e - row*36;
                const int i = row / 6, j = row - (row/6)*6;
                float ax = 0.f, ay = 0.f;
                if (i < 5 && j > 0) {
                    const float coef = sqrtf((float)((i+1)*j));
                    const float2 x = R[(row+5)*36 + c];
                    const float px = u.x*x.x - u.y*x.y;
                    const float py = u.x*x.y + u.y*x.x;
                    ax = fmaf(coef, px, ax); ay = fmaf(coef, py, ay);
                }
                if (i > 0 && j < 5) {
                    const float coef = sqrtf((float)(i*(j+1)));
                    const float2 x = R[(row-5)*36 + c];
                    const float px = w2.x*x.x - w2.y*x.y;
                    const float py = w2.x*x.y + w2.y*x.x;
                    ax = fmaf(coef, px, ax); ay = fmaf(coef, py, ay);
                }
                T[e] = make_float2(((row == c) ? 1.f : 0.f) + ax*invk, ay*invk);
            }
            __syncthreads();
            float2* tmp = R; R = T; T = tmp;
        }
        for (int s2 = 0; s2 < 6; ++s2) {
            for (int e = tid; e < 1296; e += 256) {
                const int row = e / 36, c = e - row*36;
                float ax = 0.f, ay = 0.f;
                #pragma unroll 6
                for (int k = 0; k < 36; ++k)
                    cmadd(ax, ay, R[row*36 + k], R[k*36 + c]);
                T[e] = make_float2(ax, ay);
            }
            __syncthreads();
            float2* tmp = R; R = T; T = tmp;
        }
        for (int idx = tid; idx < 146; idx += 256) {
            int nn = 0;
            while (idx >= d_BS_OFF[nn+1]) ++nn;
            const int sn  = d_BS_SN[nn];
            const int rel = idx - d_BS_OFF[nn];
            const int p = rel / sn, qq = rel % sn;
            const int imin = (nn > 5) ? (nn - 5) : 0;
            const int row = 5*(imin + p)  + nn;
            const int col = 5*(imin + qq) + nn;
            const float2 z = R[row*36 + col];
            bsh[g*292 + 2*idx    ] = (h2){(_Float16)z.x,  (_Float16)z.x};
            bsh[g*292 + 2*idx + 1] = (h2){(_Float16)(-z.y), (_Float16)z.y};
        }
    } else {
        const int t = tid;
        if (t >= 40) return;
        const int l  = t / 10;
        const int gi = t % 10;
        float2 G[36];
        if (gi < 5) {
            // Sq[m] = squeeze(r) @ diag(e^{i rphi1 * n})  (parity-banded)
            const int m = gi;
            const float r    = lin[l*63 + 24 + m];
            const float rphi = (m < 4) ? lin[l*63 + 20 + m] : 0.f;
            float R[36], T[36];
            #pragma unroll
            for (int e = 0; e < 36; ++e) R[e] = (e % 7 == 0) ? 1.f : 0.f;
            float hp[4];
            #pragma unroll
            for (int i = 0; i < 4; ++i)
                hp[i] = 0.5f * r * sqrtf((float)((i+1)*(i+2))) * 0.015625f;
            for (int k = 16; k >= 1; --k) {
                const float invk = 1.f / (float)k;
                #pragma unroll
                for (int i = 0; i < 6; ++i) {
                    #pragma unroll
                    for (int c = 0; c < 6; ++c) {
                        float a = 0.f;
                        if (i < 4)  a = fmaf( hp[i],   R[(i+2)*6 + c], a);
                        if (i >= 2) a = fmaf(-hp[i-2], R[(i-2)*6 + c], a);
                        T[i*6+c] = ((i == c) ? 1.f : 0.f) + a*invk;
                    }
                }
                #pragma unroll
                for (int e = 0; e < 36; ++e) R[e] = T[e];
            }
            for (int s2 = 0; s2 < 6; ++s2) {
                #pragma unroll
                for (int i = 0; i < 6; ++i) {
                    #pragma unroll
                    for (int c = 0; c < 6; ++c) {
                        float a = 0.f;
                        #pragma unroll
                        for (int k = 0; k < 6; ++k) a = fmaf(R[i*6+k], R[k*6+c], a);
                        T[i*6+c] = a;
                    }
                }
                #pragma unroll
                for (int e = 0; e < 36; ++e) R[e] = T[e];
            }
            #pragma unroll
            for (int c = 0; c < 6; ++c) {
                const float cc = cosf(rphi * (float)c), ss = sinf(rphi * (float)c);
                #pragma unroll
                for (int o = 0; o < 6; ++o)
                    G[o*6 + c] = make_float2(R[o*6+c]*cc, R[o*6+c]*ss);
            }
        } else {
            // Dp[m] = diag(e^{i kap n^2}) @ disp(dr,dp) @ diag(e^{i rphi2 n})
            const int m = gi - 5;
            const float dr   = lin[l*63 + 53 + m];
            const float dp   = lin[l*63 + 58 + m];
            const float rphi = (m < 4) ? lin[l*63 + 49 + m] : 0.f;
            const float kap  = (l < 3) ? act[l*5 + m] : ((m < 2) ? lact[m] : 0.f);
            const float2 al = make_float2(dr * cosf(dp), dr * sinf(dp));
            float2 R[36], T[36];
            #pragma unroll
            for (int e = 0; e < 36; ++e)
                R[e] = make_float2((e % 7 == 0) ? 1.f : 0.f, 0.f);
            float2 cm[6], cpb[6];
            #pragma unroll
            for (int i = 0; i < 6; ++i) {
                const float sm  = sqrtf((float)i)     * 0.015625f;
                const float sp2 = sqrtf((float)(i+1)) * 0.015625f;
                cm[i]  = make_float2( al.x*sm,  al.y*sm);
                cpb[i] = make_float2(-al.x*sp2, al.y*sp2);
            }
            for (int k = 16; k >= 1; --k) {
                const float invk = 1.f / (float)k;
                #pragma unroll
                for (int i = 0; i < 6; ++i) {
                    #pragma unroll
                    for (int c = 0; c < 6; ++c) {
                        float ax = 0.f, ay = 0.f;
                        if (i >= 1) cmadd(ax, ay, cm[i],  R[(i-1)*6 + c]);
                        if (i < 5)  cmadd(ax, ay, cpb[i], R[(i+1)*6 + c]);
                        T[i*6+c] = make_float2(((i == c) ? 1.f : 0.f) + ax*invk, ay*invk);
                    }
                }
                #pragma unroll
                for (int e = 0; e < 36; ++e) R[e] = T[e];
            }
            for (int s2 = 0; s2 < 6; ++s2) {
                #pragma unroll
                for (int i = 0; i < 6; ++i) {
                    #pragma unroll
                    for (int c = 0; c < 6; ++c) {
                        float ax = 0.f, ay = 0.f;
                        #pragma unroll
                        for (int k = 0; k < 6; ++k) cmadd(ax, ay, R[i*6+k], R[k*6+c]);
                        T[i*6+c] = make_float2(ax, ay);
                    }
                }
                #pragma unroll
                for (int e = 0; e < 36; ++e) R[e] = T[e];
            }
            #pragma unroll
            for (int o = 0; o < 6; ++o) {
                const float ko = kap * (float)(o*o);
                const float2 kp = make_float2(cosf(ko), sinf(ko));
                #pragma unroll
                for (int c = 0; c < 6; ++c) {
                    const float rc = rphi * (float)c;
                    const float2 rp = make_float2(cosf(rc), sinf(rc));
                    const float2 z = R[o*6 + c];
                    const float2 t1 = make_float2(kp.x*z.x - kp.y*z.y, kp.x*z.y + kp.y*z.x);
                    G[o*6 + c] = make_float2(t1.x*rp.x - t1.y*rp.y, t1.x*rp.y + t1.y*rp.x);
                }
            }
        }
        h2* outp = sgh + (l*10 + gi)*72;
        #pragma unroll
        for (int e = 0; e < 36; ++e) {
            outp[2*e    ] = (h2){(_Float16)G[e].x,  (_Float16)G[e].x};
            outp[2*e + 1] = (h2){(_Float16)(-G[e].y), (_Float16)G[e].y};
        }
    }
}

// ---------------------------------------------------------------------------
// Initial displacement (phi=0 -> real expm): column 0 per (batch, mode).
// ---------------------------------------------------------------------------
__global__ void dcol_kernel(const float* __restrict__ x,
                            float* __restrict__ dcol, const int total)
{
    const int i = blockIdx.x * 256 + threadIdx.x;
    if (i >= total) return;
    const float xv = x[i];
    float a[5];
    #pragma unroll
    for (int j = 0; j < 5; ++j) a[j] = xv * sqrtf((float)(j+1)) * 0.015625f;
    float R[36], T[36];
    #pragma unroll
    for (int e = 0; e < 36; ++e) R[e] = (e % 7 == 0) ? 1.f : 0.f;
    for (int k = 16; k >= 1; --k) {
        const float invk = 1.f / (float)k;
        #pragma unroll
        for (int r = 0; r < 6; ++r) {
            #pragma unroll
            for (int c = 0; c < 6; ++c) {
                float acc = 0.f;
                if (r >= 1) acc = fmaf( a[r-1], R[(r-1)*6 + c], acc);
                if (r < 5)  acc = fmaf(-a[r],   R[(r+1)*6 + c], acc);
                T[r*6+c] = ((r == c) ? 1.f : 0.f) + acc*invk;
            }
        }
        #pragma unroll
        for (int e = 0; e < 36; ++e) R[e] = T[e];
    }
    for (int s2 = 0; s2 < 6; ++s2) {
        #pragma unroll
        for (int r = 0; r < 6; ++r) {
            #pragma unroll
            for (int c = 0; c < 6; ++c) {
                float acc = 0.f;
                #pragma unroll
                for (int k = 0; k < 6; ++k) acc = fmaf(R[r*6+k], R[k*6+c], acc);
                T[r*6+c] = acc;
            }
        }
        #pragma unroll
        for (int e = 0; e < 36; ++e) R[e] = T[e];
    }
    #pragma unroll
    for (int j = 0; j < 6; ++j) dcol[i*6 + j] = R[j*6 + 0];
}

// ---------------------------------------------------------------------------
// Main kernel building blocks
// ---------------------------------------------------------------------------

// BS pass, block-partitioned: thread executes photon blocks selected by the
// runtime (wave-uniform) mask. Disjoint reads AND writes across halves.
template<int SA, int SB, int n>
struct BDm {
    static __device__ __forceinline__ void run(const h2* __restrict__ U,
                                               h2* __restrict__ psi,
                                               const int base, const bool act,
                                               const unsigned mask) {
        if (mask & (1u << n)) {
            constexpr int sn = BS_SN[n], uoff = BS_OFF[n];
            constexpr int imin = (n > 5) ? (n - 5) : 0;
            h2 vb[sn], vbs[sn];
            #pragma unroll
            for (int q = 0; q < sn; ++q) {
                const int c = 5*(imin + q) + n;
                vb[q] = psi[base + (c/6)*SA + (c%6)*SB];
                vbs[q] = swp(vb[q]);
            }
            h2 ob[sn];
            #pragma unroll
            for (int p = 0; p < sn; ++p) {
                h2 acc = U[2*(uoff + p*sn)] * vb[0];      // peeled first term
                acc = pkfma(U[2*(uoff + p*sn) + 1], vbs[0], acc);
                #pragma unroll
                for (int q = 1; q < sn; ++q) {
                    acc = pkfma(U[2*(uoff + p*sn + q)    ], vb[q],  acc);
                    acc = pkfma(U[2*(uoff + p*sn + q) + 1], vbs[q], acc);
                }
                ob[p] = acc;
            }
            if (act) {
                #pragma unroll
                for (int p = 0; p < sn; ++p) {
                    const int c = 5*(imin + p) + n;
                    psi[base + (c/6)*SA + (c%6)*SB] = ob[p];
                }
            }
        }
        BDm<SA, SB, n+1>::run(U, psi, base, act, mask);
    }
};
template<int SA, int SB>
struct BDm<SA, SB, 11> {
    static __device__ __forceinline__ void run(const h2*, h2*, int, bool, unsigned) {}
};

template<int SA, int SB>
__device__ __forceinline__ void pass_bs(const h2* __restrict__ U,
                                        h2* __restrict__ psi,
                                        const int base, const bool act,
                                        const unsigned mask)
{
    BDm<SA, SB, 0>::run(U, psi, base, act, mask);
    __syncthreads();
}

// single-mode gate pass: 432 active threads x 3 mode-fibers of 6 (stride SM).
// S0..S3: spectator strides (ascending digit order). SP: parity-sparse.
template<int SM, int S0, int S1, int S2, int S3, bool SP>
__device__ __forceinline__ void pass_sg(const h2* __restrict__ G,
                                        h2* __restrict__ psi,
                                        const int aidx, const bool act)
{
    #pragma unroll
    for (int j = 0; j < 3; ++j) {
        const int g = aidx + j*432;
        const int d0 = g % 6; int t = g / 6;
        const int d1 = t % 6; t /= 6;
        const int d2 = t % 6; const int d3 = t / 6;
        const int base = d0*S0 + d1*S1 + d2*S2 + d3*S3;
        h2 vb[6], vbs[6];
        #pragma unroll
        for (int k = 0; k < 6; ++k) { vb[k] = psi[base + k*SM]; vbs[k] = swp(vb[k]); }
        h2 o6[6];
        #pragma unroll
        for (int o = 0; o < 6; ++o) {
            const int k0 = SP ? (o & 1) : 0;
            const int st = SP ? 2 : 1;
            h2 acc = G[2*(o*6 + k0)] * vb[k0];            // peeled first term
            acc = pkfma(G[2*(o*6 + k0) + 1], vbs[k0], acc);
            #pragma unroll
            for (int k = k0 + st; k < 6; k += st) {
                acc = pkfma(G[2*(o*6 + k)    ], vb[k],  acc);
                acc = pkfma(G[2*(o*6 + k) + 1], vbs[k], acc);
            }
            o6[o] = acc;
        }
        if (act) {
            #pragma unroll
            for (int o = 0; o < 6; ++o) psi[base + o*SM] = o6[o];
        }
    }
    __syncthreads();
}

__global__ __launch_bounds__(512, 8)
void qnet_kernel(const h2* __restrict__ bs,
                 const h2* __restrict__ sg,
                 const float* __restrict__ dcol,
                 float* __restrict__ out)
{
    // addr = 6*i0 + i1 + 36*i2 + 221*i3 + 1334*i4 (max 7990); scratch after
    __shared__ __align__(16) h2 psi[8088];   // 32352 B -> 4 blocks x 8 waves/CU
    const int tid = threadIdx.x;
    const int b   = blockIdx.x;

    float* stf = (float*)(psi + 7992);   // 30 floats (h2 units 7992..8051)
    float* red = (float*)(psi + 8052);   // 16 floats (h2 units 8052..8083)

    if (tid < 30) stf[tid] = dcol[b*30 + tid];
    __syncthreads();
    for (int e = tid; e < 7776; e += 512) {
        int t = e;
        const int i4 = t % 6; t /= 6;
        const int i3 = t % 6; t /= 6;
        const int i2 = t % 6; t /= 6;
        const int i1 = t % 6; t /= 6;
        const int i0 = t;
        const int addr = 6*i0 + i1 + 36*i2 + 221*i3 + 1334*i4;
        const float val = stf[i0]*stf[6+i1]*stf[12+i2]*stf[18+i3]*stf[24+i4];
        psi[addr] = (h2){(_Float16)val, (_Float16)0.f};
    }
    __syncthreads();

    // thread mapping: two halves of 256; sub<216 active; fiber f = sub
    const int sub   = tid & 255;
    const int halfT = tid >> 8;                 // wave-uniform
    const bool act  = sub < 216;
    const int f = act ? sub : 215;
    const int fa = f / 36, rem = f - fa*36;
    const int fb = rem / 6, fc = rem - fb*6;
    const int baseK0 = fa*36 + fb*221 + fc*1334;   // pair (0,1): spect 2,3,4
    const int baseK1 = fa*6  + fb*221 + fc*1334;   // pair (1,2): spect 0,3,4
    const int baseK2 = rem   + fa*1334;            // pair (2,3): spect 0,1 (contig), 4
    const int baseK3 = f;                          // pair (3,4): spect 0,1,2 (contig)
    const unsigned mask = halfT ? MASK_B : MASK_A;
    const int aidx = halfT*216 + f;                // 0..431 for single passes

    for (int l = 0; l < 4; ++l) {
        const h2* bsl = bs + l * 20 * 292;
        const h2* sgl = sg + l * 10 * 72;
        for (int hf = 0; hf < 2; ++hf) {
            const h2* bh = bsl + hf * 10 * 292;
            const h2* sh = sgl + hf * 5 * 72;
            // rail order k = {0,2,1,3,0,2,1,3,0,2}
            pass_bs<6,1>     (bh + 0*292, psi, baseK0, act, mask);
            pass_bs<36,221>  (bh + 1*292, psi, baseK2, act, mask);
            pass_bs<1,36>    (bh + 2*292, psi, baseK1, act, mask);
            pass_bs<221,1334>(bh + 3*292, psi, baseK3, act, mask);
            pass_bs<6,1>     (bh + 4*292, psi, baseK0, act, mask);
            pass_bs<36,221>  (bh + 5*292, psi, baseK2, act, mask);
            pass_bs<1,36>    (bh + 6*292, psi, baseK1, act, mask);
            pass_bs<221,1334>(bh + 7*292, psi, baseK3, act, mask);
            pass_bs<6,1>     (bh + 8*292, psi, baseK0, act, mask);
            pass_bs<36,221>  (bh + 9*292, psi, baseK2, act, mask);
            if (hf == 0) {   // squeeze gates: parity-sparse
                pass_sg<6,    1,36,221,1334, true>(sh + 0*72, psi, aidx, act);
                pass_sg<1,    6,36,221,1334, true>(sh + 1*72, psi, aidx, act);
                pass_sg<36,   1,6,221,1334,  true>(sh + 2*72, psi, aidx, act);
                pass_sg<221,  1,6,36,1334,   true>(sh + 3*72, psi, aidx, act);
                pass_sg<1334, 1,6,36,221,    true>(sh + 4*72, psi, aidx, act);
            } else {         // displacement gates: dense
                pass_sg<6,    1,36,221,1334, false>(sh + 0*72, psi, aidx, act);
                pass_sg<1,    6,36,221,1334, false>(sh + 1*72, psi, aidx, act);
                pass_sg<36,   1,6,221,1334,  false>(sh + 2*72, psi, aidx, act);
                pass_sg<221,  1,6,36,1334,   false>(sh + 3*72, psi, aidx, act);
                pass_sg<1334, 1,6,36,221,    false>(sh + 4*72, psi, aidx, act);
            }
        }
    }

    // <psi| X psi> on modes 0 (stride 6) and 1 (stride 1)
    float s0 = 0.f, s1 = 0.f;
    for (int fr = tid; fr < 1296; fr += 512) {
        const int q0 = fr % 6;
        const int q1 = (fr / 6) % 6;
        const int q2 = (fr / 36) % 6;
        const int q3 = fr / 216;
        const int base0 = q0*1 + q1*36 + q2*221 + q3*1334;   // spectators of mode 0
        #pragma unroll
        for (int j = 0; j < 5; ++j) {
            const vf2 p0 = h2f(psi[base0 + 6*j]);
            const vf2 p1 = h2f(psi[base0 + 6*(j+1)]);
            s0 = fmaf(sqrtf((float)(j+1)), fmaf(p0.y, p1.y, p0.x*p1.x), s0);
        }
        const int base1 = q0*6 + q1*36 + q2*221 + q3*1334;   // spectators of mode 1
        #pragma unroll
        for (int j = 0; j < 5; ++j) {
            const vf2 p0 = h2f(psi[base1 + j]);
            const vf2 p1 = h2f(psi[base1 + j + 1]);
            s1 = fmaf(sqrtf((float)(j+1)), fmaf(p0.y, p1.y, p0.x*p1.x), s1);
        }
    }
    #pragma unroll
    for (int off = 32; off > 0; off >>= 1) {
        s0 += __shfl_down(s0, off, 64);
        s1 += __shfl_down(s1, off, 64);
    }
    if ((tid & 63) == 0) { red[(tid>>6)*2] = s0; red[(tid>>6)*2 + 1] = s1; }
    __syncthreads();
    if (tid == 0) {
        float r0 = 0.f, r1 = 0.f;
        #pragma unroll
        for (int w = 0; w < 8; ++w) { r0 += red[2*w]; r1 += red[2*w + 1]; }
        out[b*2 + 0] = 2.f * r0;
        out[b*2 + 1] = 2.f * r1;
    }
}

// ---------------------------------------------------------------------------
extern "C" void kernel_launch(void* const* d_in, const int* in_sizes, int n_in,
                              void* d_out, int out_size, void* d_ws, size_t ws_size,
                              hipStream_t stream)
{
    const float* x    = (const float*)d_in[0];   // (B, 5)
    const float* lin  = (const float*)d_in[1];   // (4, 63)
    const float* act  = (const float*)d_in[2];   // (3, 5)
    const float* lact = (const float*)d_in[3];   // (5,)
    float* out = (float*)d_out;                  // (B, 2) float32

    const int B = in_sizes[0] / 5;

    // ws layout: 80 BS gates (292 h2) | 40 single gates (72 h2) | dcol f32
    h2*    bsh = (h2*)d_ws;
    h2*    sgh = bsh + 80*292;
    float* dc  = (float*)(sgh + 40*72);

    gates_kernel<<<dim3(81), dim3(256), 0, stream>>>(lin, act, lact, bsh, sgh);
    const int total = B * 5;
    dcol_kernel<<<dim3((total + 255)/256), dim3(256), 0, stream>>>(x, dc, total);
    qnet_kernel<<<dim3(B), dim3(512), 0, stream>>>(bsh, sgh, dc, out);
}